// Round 9
// baseline (257.806 us; speedup 1.0000x reference)
//
#include <hip/hip_runtime.h>
#include <hip/hip_bf16.h>

#define STC_N     5000
#define STC_TIN   16
#define STC_T1    14
#define STC_T2    12
#define STC_CIN   16
#define STC_CH    32
#define STC_CO    64
#define STC_BT1   56
#define STC_BT2   48
#define STC_RT1   17500      /* 280000/16 row-tiles */
#define STC_GBLK  1280
#define STC_GWAVE (STC_GBLK*4)
#define STC_ROWB1 1792       /* BT1*CH elements per node (transposed layout) */

#define STC_OFF_DEG   0
#define STC_OFF_CNT   20000
#define STC_OFF_CUR   40000
#define STC_OFF_DIS   60000
#define STC_OFF_OFFS  80000
#define STC_OFF_WN    100032
#define STC_OFF_CCOL  420032
#define STC_OFF_CW    740032
#define STC_OFF_T0    1060096
#define STC_OFF_G1    (STC_OFF_T0 + 17920000)
#define STC_OFF_G2    (STC_OFF_G1 + 17920000)
#define STC_OFF_PK2   (STC_OFF_G2 + 17920000)   /* 36 frags * 512 B */
#define STC_OFF_PK1   (STC_OFF_PK2 + 36864)     /* 12 frags */
#define STC_OFF_PKC   (STC_OFF_PK1 + 12288)     /* 6 frags */
#define STC_WS_REQ    (STC_OFF_PKC + 6144)

typedef __hip_bfloat16 bf16;
typedef short stc_s8 __attribute__((ext_vector_type(8)));
typedef float stc_f4 __attribute__((ext_vector_type(4)));

__device__ float stc_lo16(unsigned u) { return __uint_as_float(u << 16); }
__device__ float stc_hi16(unsigned u) { return __uint_as_float(u & 0xffff0000u); }
__device__ float stc_s2f(short s) {
    return __uint_as_float(((unsigned)(unsigned short)s) << 16);
}

__device__ short stc_f2bs(float f) {          /* f32 -> bf16 bits, RNE */
    unsigned u = __float_as_uint(f);
    u = (u + 0x7FFFu + ((u >> 16) & 1u)) >> 16;
    return (short)u;
}

__global__ void STConv_9972914061616_kernel() {}

__global__ void stc_fill(float* out, int n, float val) {
    int i = blockIdx.x * 256 + threadIdx.x;
    if (i < n) out[i] = val;
}

/* merged zero (blocks 0..58) + weight pack (blocks 59..72); independent work */
__global__ void stc_init(int* zp,
                         const float* w1a, const float* w1b, const float* w1c,
                         const float* w2a, const float* w2b, const float* w2c,
                         const float* chW,
                         short* pk1, short* pk2, short* pkc) {
    if (blockIdx.x < 59) {
        int i = blockIdx.x * 256 + threadIdx.x;
        if (i < 15000) zp[i] = 0;
        return;
    }
    int gid = (blockIdx.x - 59) * 256 + threadIdx.x;
    if (gid >= 54 * 64) return;
    int fi = gid >> 6;
    int lane = gid & 63;
    int j = lane & 15;
    int quad = lane >> 4;
    short f[8];
    if (fi < 36) {
        int s = fi % 3;
        int cc4 = fi / 3;
        int conv = cc4 >> 2;
        int c4 = cc4 & 3;
        const float* Wp = (conv == 0) ? w2a : ((conv == 1) ? w2b : w2c);
        int och = c4 * 16 + j;
        for (int i = 0; i < 8; ++i) {
            int cc = quad * 8 + i;
            f[i] = stc_f2bs(Wp[och * 96 + cc * 3 + s]);
        }
        for (int i = 0; i < 8; ++i) pk2[(fi * 64 + lane) * 8 + i] = f[i];
    } else if (fi < 48) {
        int t = fi - 36;
        int s = t & 1;
        int cj = t >> 1;
        int conv = cj >> 1;
        int jt = cj & 1;
        const float* Wp = (conv == 0) ? w1a : ((conv == 1) ? w1b : w1c);
        int och = jt * 16 + j;
        for (int i = 0; i < 8; ++i) {
            int k = s * 32 + quad * 8 + i;
            int kt = k >> 4;
            int c = k & 15;
            f[i] = (kt < 3) ? stc_f2bs(Wp[och * 48 + c * 3 + kt]) : (short)0;
        }
        for (int i = 0; i < 8; ++i) pk1[(t * 64 + lane) * 8 + i] = f[i];
    } else {
        int t = fi - 48;
        int s = t >> 1;
        int jt = t & 1;
        int d = jt * 16 + j;
        for (int i = 0; i < 8; ++i) {
            int c = quad * 8 + i;
            float w0 = chW[c * 32 + d];
            float w1 = chW[1024 + c * 32 + d];
            float w2 = chW[2048 + c * 32 + d];
            float v = (s == 0) ? (w0 - w2) : ((s == 1) ? -w1 : 2.0f * w2);
            f[i] = stc_f2bs(v);
        }
        for (int i = 0; i < 8; ++i) pkc[(t * 64 + lane) * 8 + i] = f[i];
    }
}

/* degree + count in one pass */
__global__ void stc_deg(const int* ei, const float* ew, float* deg, int* cnt, int E) {
    int e = blockIdx.x * 256 + threadIdx.x;
    if (e < E) {
        int r = ei[e];
        atomicAdd(&deg[r], ew[e]);
        atomicAdd(&cnt[r], 1);
    }
}

/* one-pass scan: 20 elems/thread in registers, ONE 8-round block scan */
__global__ void stc_scan(const int* cnt, int* offs, int n) {
    __shared__ int s[256];
    int tid = threadIdx.x;
    int base = tid * 20;
    int loc[20];
    int sum = 0;
#pragma unroll
    for (int k = 0; k < 20; ++k) {
        int i = base + k;
        int v = (i < n) ? cnt[i] : 0;
        loc[k] = sum;
        sum += v;
    }
    s[tid] = sum;
    __syncthreads();
    for (int off = 1; off < 256; off <<= 1) {
        int t = (tid >= off) ? s[tid - off] : 0;
        __syncthreads();
        s[tid] += t;
        __syncthreads();
    }
    int pre = (tid > 0) ? s[tid - 1] : 0;
#pragma unroll
    for (int k = 0; k < 20; ++k) {
        int i = base + k;
        if (i < n) offs[i] = pre + loc[k];
    }
    if (tid == 255) offs[n] = s[255];
}

/* scatter with inline sym-norm weight (deg is 20 KB, L2-hot) */
__global__ void stc_scatter(const int* ei, const float* ew, const float* deg,
                            const int* offs, int* cursor, int* ccol, float* cw,
                            int E) {
    int e = blockIdx.x * 256 + threadIdx.x;
    if (e < E) {
        int r = ei[e];
        int c = ei[E + e];
        float dr = deg[r];
        float dc = deg[c];
        float ir = (dr > 0.0f) ? rsqrtf(dr) : 0.0f;
        float ic = (dc > 0.0f) ? rsqrtf(dc) : 0.0f;
        int pos = atomicAdd(&cursor[r], 1);
        int slot = offs[r] + pos;
        ccol[slot] = c;
        cw[slot] = ir * ew[e] * ic;
    }
}

/* tconv1 as MFMA GEMM: C[280000 x 96] = A[280000 x 48] * B[48 x 96]. */
__global__ __launch_bounds__(256, 2) void stc_tconv1m(
    const float* X, const short* pk1,
    const float* B1, const float* B2, const float* B3,
    bf16* T0) {
    int lane = threadIdx.x & 63;
    int j = lane & 15;
    int quad = lane >> 4;
    int wave = blockIdx.x * 4 + (threadIdx.x >> 6);

    stc_s8 bfrag[3][2][2];
    for (int conv = 0; conv < 3; ++conv)
        for (int jt = 0; jt < 2; ++jt)
            for (int s = 0; s < 2; ++s) {
                int t = (conv * 2 + jt) * 2 + s;
                bfrag[conv][jt][s] = *(const stc_s8*)(pk1 + (t * 64 + lane) * 8);
            }
    float pb[2], qb[2], rb[2];
    for (int jt = 0; jt < 2; ++jt) {
        int och = jt * 16 + j;
        pb[jt] = B1[och];
        qb[jt] = B2[och];
        rb[jt] = B3[och];
    }

    for (int rt = wave; rt < STC_RT1; rt += STC_GWAVE) {
        int rm = rt * 16 + j;
        int n = rm % STC_N;
        int bt = rm / STC_N;
        int t = bt % STC_T1;
        int b = bt / STC_T1;

        int kt0 = quad >> 1;
        int c0 = (quad & 1) * 8;
        const float* xp0 = X + ((size_t)((b * STC_TIN + t + kt0) * STC_N + n)) * STC_CIN + c0;
        stc_s8 af0;
        for (int i = 0; i < 8; ++i) af0[i] = stc_f2bs(xp0[i]);

        stc_s8 af1;
        if (quad < 2) {
            const float* xp1 = X + ((size_t)((b * STC_TIN + t + 2) * STC_N + n)) * STC_CIN + c0;
            for (int i = 0; i < 8; ++i) af1[i] = stc_f2bs(xp1[i]);
        } else {
            for (int i = 0; i < 8; ++i) af1[i] = 0;
        }

        stc_f4 acc[6];
        for (int a = 0; a < 6; ++a) acc[a] = (stc_f4){0.0f, 0.0f, 0.0f, 0.0f};
        for (int conv = 0; conv < 3; ++conv) {
            for (int jt = 0; jt < 2; ++jt) {
                int a = conv * 2 + jt;
                acc[a] = __builtin_amdgcn_mfma_f32_16x16x32_bf16(
                    af0, bfrag[conv][jt][0], acc[a], 0, 0, 0);
                acc[a] = __builtin_amdgcn_mfma_f32_16x16x32_bf16(
                    af1, bfrag[conv][jt][1], acc[a], 0, 0, 0);
            }
        }

        for (int jt = 0; jt < 2; ++jt) {
            for (int reg = 0; reg < 4; ++reg) {
                float P = acc[jt][reg] + pb[jt];
                float Q = acc[2 + jt][reg] + qb[jt];
                float R = acc[4 + jt][reg] + rb[jt];
                float Qc = fminf(fmaxf(Q, -30.0f), 30.0f);
                float sg = 1.0f / (1.0f + __expf(-Qc));
                float h = P * sg + R;
                if (h < 0.0f) h = 0.0f;
                int row = rt * 16 + quad * 4 + reg;
                int nw = row % STC_N;
                int btw = row / STC_N;
                T0[(size_t)nw * STC_ROWB1 + btw * STC_CH + jt * 16 + j] =
                    __float2bfloat16(h);
            }
        }
    }
}

/* gather, 512-thread / uint2 / unroll-8 version: thread (sl,cg8) owns
   slot sl (0..63, <56 active) x 4 channels (8 B).  8-deep independent
   loads at ~45 VGPR keeps 8 waves/SIMD -> 2x in-flight loads vs the
   uint4/unroll-4 form (which was scattered-load latency-bound). */
__global__ __launch_bounds__(512, 2) void stc_gatherv(
    const bf16* z, bf16* g, const int* offs,
    const int* ccol, const float* cw) {
    int n = blockIdx.x;
    __shared__ int col_s[128];
    __shared__ float w_s[128];
    int beg = offs[n];
    int end = offs[n + 1];
    int cg = threadIdx.x & 7;
    int sl = threadIdx.x >> 3;
    int act = (sl < STC_BT1);
    float a0 = 0.f, a1 = 0.f, a2 = 0.f, a3 = 0.f;
    const bf16* zb = z + sl * STC_CH + cg * 4;
    for (int chunk = beg; chunk < end; chunk += 128) {
        int m = end - chunk;
        if (m > 128) m = 128;
        if (threadIdx.x < m) {
            col_s[threadIdx.x] = ccol[chunk + threadIdx.x];
            w_s[threadIdx.x] = cw[chunk + threadIdx.x];
        }
        __syncthreads();
        if (act) {
            int i = 0;
            for (; i + 8 <= m; i += 8) {
                uint2 u0 = *(const uint2*)(zb + (size_t)col_s[i] * STC_ROWB1);
                uint2 u1 = *(const uint2*)(zb + (size_t)col_s[i + 1] * STC_ROWB1);
                uint2 u2 = *(const uint2*)(zb + (size_t)col_s[i + 2] * STC_ROWB1);
                uint2 u3 = *(const uint2*)(zb + (size_t)col_s[i + 3] * STC_ROWB1);
                uint2 u4 = *(const uint2*)(zb + (size_t)col_s[i + 4] * STC_ROWB1);
                uint2 u5 = *(const uint2*)(zb + (size_t)col_s[i + 5] * STC_ROWB1);
                uint2 u6 = *(const uint2*)(zb + (size_t)col_s[i + 6] * STC_ROWB1);
                uint2 u7 = *(const uint2*)(zb + (size_t)col_s[i + 7] * STC_ROWB1);
                float w0 = w_s[i],     w1 = w_s[i + 1], w2 = w_s[i + 2], w3 = w_s[i + 3];
                float w4 = w_s[i + 4], w5 = w_s[i + 5], w6 = w_s[i + 6], w7 = w_s[i + 7];
                a0 += w0 * stc_lo16(u0.x); a1 += w0 * stc_hi16(u0.x);
                a2 += w0 * stc_lo16(u0.y); a3 += w0 * stc_hi16(u0.y);
                a0 += w1 * stc_lo16(u1.x); a1 += w1 * stc_hi16(u1.x);
                a2 += w1 * stc_lo16(u1.y); a3 += w1 * stc_hi16(u1.y);
                a0 += w2 * stc_lo16(u2.x); a1 += w2 * stc_hi16(u2.x);
                a2 += w2 * stc_lo16(u2.y); a3 += w2 * stc_hi16(u2.y);
                a0 += w3 * stc_lo16(u3.x); a1 += w3 * stc_hi16(u3.x);
                a2 += w3 * stc_lo16(u3.y); a3 += w3 * stc_hi16(u3.y);
                a0 += w4 * stc_lo16(u4.x); a1 += w4 * stc_hi16(u4.x);
                a2 += w4 * stc_lo16(u4.y); a3 += w4 * stc_hi16(u4.y);
                a0 += w5 * stc_lo16(u5.x); a1 += w5 * stc_hi16(u5.x);
                a2 += w5 * stc_lo16(u5.y); a3 += w5 * stc_hi16(u5.y);
                a0 += w6 * stc_lo16(u6.x); a1 += w6 * stc_hi16(u6.x);
                a2 += w6 * stc_lo16(u6.y); a3 += w6 * stc_hi16(u6.y);
                a0 += w7 * stc_lo16(u7.x); a1 += w7 * stc_hi16(u7.x);
                a2 += w7 * stc_lo16(u7.y); a3 += w7 * stc_hi16(u7.y);
            }
            for (; i < m; ++i) {
                float w = w_s[i];
                uint2 u = *(const uint2*)(zb + (size_t)col_s[i] * STC_ROWB1);
                a0 += w * stc_lo16(u.x); a1 += w * stc_hi16(u.x);
                a2 += w * stc_lo16(u.y); a3 += w * stc_hi16(u.y);
            }
        }
        __syncthreads();
    }
    if (act) {
        unsigned p0 = ((unsigned)(unsigned short)stc_f2bs(a0)) |
                      (((unsigned)(unsigned short)stc_f2bs(a1)) << 16);
        unsigned p1 = ((unsigned)(unsigned short)stc_f2bs(a2)) |
                      (((unsigned)(unsigned short)stc_f2bs(a3)) << 16);
        uint2 o;
        o.x = p0; o.y = p1;
        *(uint2*)(g + (size_t)n * STC_ROWB1 + sl * STC_CH + cg * 4) = o;
    }
}

/* Fused second gather + cheb-combine + tconv2 + per-node BN, 512-thread.
   Phase G: all 8 waves gather A*G1 for node n (uint2/unroll-8) -> LDS g2
            (sl>=56 lanes write zeros; their rows are never consumed).
   Phase A: waves 0..3 combine row-tile t3=w (a2 frag from LDS g2).
   Phase B: waves 0..3, wave w owns c4 slice w for all 3 bt2-tiles.
   Phase C: all 512 threads: block BN -> normalized write to d_out.
   Barriers are outside the wave guards (uniform execution). */
__global__ __launch_bounds__(512, 2) void stc_gcombconv2bn(
    const bf16* T0, const bf16* G1,
    const int* offs, const int* ccol, const float* cw,
    const short* pkc, const float* chB,
    const short* pk2, const float* B1, const float* B2, const float* B3,
    const float* gamma, const float* beta, float* T2) {
    __shared__ short comb[64 * 40];   /* 5120 B */
    __shared__ short g2[64 * 40];     /* 5120 B */
    __shared__ short hb[48 * 72];     /* 6912 B */
    __shared__ int col_s[128];
    __shared__ float w_s[128];
    __shared__ float redm[4];
    __shared__ float redv[8];
    int lane = threadIdx.x & 63;
    int j = lane & 15;
    int quad = lane >> 4;
    int w = threadIdx.x >> 6;         /* 0..7 */
    int n = blockIdx.x;               /* grid = 5000 blocks, 1 node each */

    /* ---- phase G: gather G2 rows for node n from G1 (all 8 waves) ---- */
    {
        int beg = offs[n];
        int end = offs[n + 1];
        int cg = threadIdx.x & 7;
        int sl = threadIdx.x >> 3;
        int act = (sl < STC_BT1);
        float a0 = 0.f, a1 = 0.f, a2 = 0.f, a3 = 0.f;
        const bf16* zb = G1 + sl * STC_CH + cg * 4;
        for (int chunk = beg; chunk < end; chunk += 128) {
            int m = end - chunk;
            if (m > 128) m = 128;
            if (threadIdx.x < m) {
                col_s[threadIdx.x] = ccol[chunk + threadIdx.x];
                w_s[threadIdx.x] = cw[chunk + threadIdx.x];
            }
            __syncthreads();
            if (act) {
                int i = 0;
                for (; i + 8 <= m; i += 8) {
                    uint2 u0 = *(const uint2*)(zb + (size_t)col_s[i] * STC_ROWB1);
                    uint2 u1 = *(const uint2*)(zb + (size_t)col_s[i + 1] * STC_ROWB1);
                    uint2 u2 = *(const uint2*)(zb + (size_t)col_s[i + 2] * STC_ROWB1);
                    uint2 u3 = *(const uint2*)(zb + (size_t)col_s[i + 3] * STC_ROWB1);
                    uint2 u4 = *(const uint2*)(zb + (size_t)col_s[i + 4] * STC_ROWB1);
                    uint2 u5 = *(const uint2*)(zb + (size_t)col_s[i + 5] * STC_ROWB1);
                    uint2 u6 = *(const uint2*)(zb + (size_t)col_s[i + 6] * STC_ROWB1);
                    uint2 u7 = *(const uint2*)(zb + (size_t)col_s[i + 7] * STC_ROWB1);
                    float w0 = w_s[i],     w1 = w_s[i + 1], w2 = w_s[i + 2], w3 = w_s[i + 3];
                    float w4 = w_s[i + 4], w5 = w_s[i + 5], w6 = w_s[i + 6], w7 = w_s[i + 7];
                    a0 += w0 * stc_lo16(u0.x); a1 += w0 * stc_hi16(u0.x);
                    a2 += w0 * stc_lo16(u0.y); a3 += w0 * stc_hi16(u0.y);
                    a0 += w1 * stc_lo16(u1.x); a1 += w1 * stc_hi16(u1.x);
                    a2 += w1 * stc_lo16(u1.y); a3 += w1 * stc_hi16(u1.y);
                    a0 += w2 * stc_lo16(u2.x); a1 += w2 * stc_hi16(u2.x);
                    a2 += w2 * stc_lo16(u2.y); a3 += w2 * stc_hi16(u2.y);
                    a0 += w3 * stc_lo16(u3.x); a1 += w3 * stc_hi16(u3.x);
                    a2 += w3 * stc_lo16(u3.y); a3 += w3 * stc_hi16(u3.y);
                    a0 += w4 * stc_lo16(u4.x); a1 += w4 * stc_hi16(u4.x);
                    a2 += w4 * stc_lo16(u4.y); a3 += w4 * stc_hi16(u4.y);
                    a0 += w5 * stc_lo16(u5.x); a1 += w5 * stc_hi16(u5.x);
                    a2 += w5 * stc_lo16(u5.y); a3 += w5 * stc_hi16(u5.y);
                    a0 += w6 * stc_lo16(u6.x); a1 += w6 * stc_hi16(u6.x);
                    a2 += w6 * stc_lo16(u6.y); a3 += w6 * stc_hi16(u6.y);
                    a0 += w7 * stc_lo16(u7.x); a1 += w7 * stc_hi16(u7.x);
                    a2 += w7 * stc_lo16(u7.y); a3 += w7 * stc_hi16(u7.y);
                }
                for (; i < m; ++i) {
                    float wv = w_s[i];
                    uint2 u = *(const uint2*)(zb + (size_t)col_s[i] * STC_ROWB1);
                    a0 += wv * stc_lo16(u.x); a1 += wv * stc_hi16(u.x);
                    a2 += wv * stc_lo16(u.y); a3 += wv * stc_hi16(u.y);
                }
            }
            __syncthreads();
        }
        /* inactive lanes (sl>=56) accumulated nothing -> write zeros */
        unsigned p0 = ((unsigned)(unsigned short)stc_f2bs(a0)) |
                      (((unsigned)(unsigned short)stc_f2bs(a1)) << 16);
        unsigned p1 = ((unsigned)(unsigned short)stc_f2bs(a2)) |
                      (((unsigned)(unsigned short)stc_f2bs(a3)) << 16);
        uint2 o;
        o.x = p0; o.y = p1;
        *(uint2*)(g2 + sl * 40 + cg * 4) = o;
    }
    __syncthreads();

    /* ---- phase A: waves 0..3, wave w combines tile t3 = w ---- */
    if (w < 4) {
        stc_s8 cfrag[3][2];
        for (int s = 0; s < 3; ++s)
            for (int jt = 0; jt < 2; ++jt)
                cfrag[s][jt] = *(const stc_s8*)(pkc + ((s * 2 + jt) * 64 + lane) * 8);
        float bl0 = chB[j];
        float bl1 = chB[16 + j];
        size_t rm = (size_t)n * STC_BT1 + w * 16 + j;
        size_t abase = rm * STC_CH + quad * 8;
        stc_s8 a0 = *(const stc_s8*)(T0 + abase);
        stc_s8 a1 = *(const stc_s8*)(G1 + abase);
        stc_s8 a2 = *(const stc_s8*)(g2 + (w * 16 + j) * 40 + quad * 8);
        stc_f4 acc[2];
        acc[0] = (stc_f4){0.0f, 0.0f, 0.0f, 0.0f};
        acc[1] = (stc_f4){0.0f, 0.0f, 0.0f, 0.0f};
        for (int jt = 0; jt < 2; ++jt) {
            acc[jt] = __builtin_amdgcn_mfma_f32_16x16x32_bf16(a0, cfrag[0][jt], acc[jt], 0, 0, 0);
            acc[jt] = __builtin_amdgcn_mfma_f32_16x16x32_bf16(a1, cfrag[1][jt], acc[jt], 0, 0, 0);
            acc[jt] = __builtin_amdgcn_mfma_f32_16x16x32_bf16(a2, cfrag[2][jt], acc[jt], 0, 0, 0);
        }
        for (int jt = 0; jt < 2; ++jt) {
            float bl = (jt == 0) ? bl0 : bl1;
            for (int reg = 0; reg < 4; ++reg) {
                float h = acc[jt][reg] + bl;
                if (h < 0.0f) h = 0.0f;
                int row = w * 16 + quad * 4 + reg;
                comb[row * 40 + jt * 16 + j] = stc_f2bs(h);
            }
        }
    }
    __syncthreads();

    /* ---- phase B: waves 0..3, wave w owns c4 = w ---- */
    if (w < 4) {
        stc_s8 bfrag[3][3];   /* [conv][s] */
        for (int conv = 0; conv < 3; ++conv)
            for (int s = 0; s < 3; ++s) {
                int fi = (conv * 4 + w) * 3 + s;
                bfrag[conv][s] = *(const stc_s8*)(pk2 + (fi * 64 + lane) * 8);
            }
        int och = w * 16 + j;
        float pb = B1[och];
        float qb = B2[och];
        float rb = B3[och];

        float lsum = 0.0f;
        for (int t3 = 0; t3 < 3; ++t3) {
            int btb = t3 * 16;
            int bt2 = btb + j;
            int b = bt2 / STC_T2;
            int t = bt2 % STC_T2;
            const short* ap = comb + (b * STC_T1 + t) * 40 + quad * 8;
            stc_s8 af0 = *(const stc_s8*)(ap);
            stc_s8 af1 = *(const stc_s8*)(ap + 40);
            stc_s8 af2 = *(const stc_s8*)(ap + 80);

            stc_f4 acc[3];   /* P, Q, R for this c4 slice */
            for (int a = 0; a < 3; ++a) acc[a] = (stc_f4){0.0f, 0.0f, 0.0f, 0.0f};
            for (int conv = 0; conv < 3; ++conv) {
                acc[conv] = __builtin_amdgcn_mfma_f32_16x16x32_bf16(
                    af0, bfrag[conv][0], acc[conv], 0, 0, 0);
                acc[conv] = __builtin_amdgcn_mfma_f32_16x16x32_bf16(
                    af1, bfrag[conv][1], acc[conv], 0, 0, 0);
                acc[conv] = __builtin_amdgcn_mfma_f32_16x16x32_bf16(
                    af2, bfrag[conv][2], acc[conv], 0, 0, 0);
            }

            for (int reg = 0; reg < 4; ++reg) {
                float P = acc[0][reg] + pb;
                float Q = acc[1][reg] + qb;
                float R = acc[2][reg] + rb;
                float Qc = fminf(fmaxf(Q, -30.0f), 30.0f);
                float sg = 1.0f / (1.0f + __expf(-Qc));
                float h = P * sg + R;
                if (h < 0.0f) h = 0.0f;
                short hs = stc_f2bs(h);
                int row = btb + quad * 4 + reg;
                hb[row * 72 + w * 16 + j] = hs;
                lsum += stc_s2f(hs);
            }
        }
        for (int off = 32; off; off >>= 1) lsum += __shfl_xor(lsum, off);
        if (lane == 0) redm[w] = lsum;
    }
    __syncthreads();

    float mean = (redm[0] + redm[1] + redm[2] + redm[3]) * (1.0f / (STC_BT2 * STC_CO));

    /* ---- phase C: variance + write, all 512 threads (6 elems each) ---- */
    int colc = threadIdx.x & 63;
    int rw0 = threadIdx.x >> 6;      /* 0..7 */
    float sq = 0.0f;
    for (int it = 0; it < 6; ++it) {
        int row = it * 8 + rw0;
        float d = stc_s2f(hb[row * 72 + colc]) - mean;
        sq += d * d;
    }
    for (int off = 32; off; off >>= 1) sq += __shfl_xor(sq, off);
    if (lane == 0) redv[w] = sq;
    __syncthreads();
    float var = (redv[0] + redv[1] + redv[2] + redv[3] +
                 redv[4] + redv[5] + redv[6] + redv[7]) * (1.0f / (STC_BT2 * STC_CO));
    float istd = rsqrtf(var + 1e-5f);
    float scale = istd * gamma[n];
    float shift = beta[n] - mean * scale;
    for (int it = 0; it < 6; ++it) {
        int row = it * 8 + rw0;
        T2[((size_t)row * STC_N + n) * STC_CO + colc] =
            stc_s2f(hb[row * 72 + colc]) * scale + shift;
    }
}

extern "C" void kernel_launch(void* const* d_in, const int* in_sizes, int n_in,
                              void* d_out, int out_size, void* d_ws, size_t ws_size,
                              hipStream_t stream) {
    float* out = (float*)d_out;
    int outb = (out_size + 255) / 256;

    if (n_in < 19) {
        stc_fill<<<outb, 256, 0, stream>>>(out, out_size, 60.0f);
        return;
    }
    if (ws_size < (size_t)STC_WS_REQ) {
        stc_fill<<<outb, 256, 0, stream>>>(out, out_size, 50.0f);
        return;
    }

    const float* X = (const float*)d_in[0];
    const int* ei = (const int*)d_in[1];
    const float* ew = (const float*)d_in[2];
    const float* w1a = (const float*)d_in[3];
    const float* b1a = (const float*)d_in[4];
    const float* w1b = (const float*)d_in[5];
    const float* b1b = (const float*)d_in[6];
    const float* w1c = (const float*)d_in[7];
    const float* b1c = (const float*)d_in[8];
    const float* chW = (const float*)d_in[9];
    const float* chB = (const float*)d_in[10];
    const float* w2a = (const float*)d_in[11];
    const float* b2a = (const float*)d_in[12];
    const float* w2b = (const float*)d_in[13];
    const float* b2b = (const float*)d_in[14];
    const float* w2c = (const float*)d_in[15];
    const float* b2c = (const float*)d_in[16];
    const float* gam = (const float*)d_in[17];
    const float* bet = (const float*)d_in[18];
    int E = in_sizes[1] / 2;

    char* ws = (char*)d_ws;
    float* deg = (float*)(ws + STC_OFF_DEG);
    int* cnt = (int*)(ws + STC_OFF_CNT);
    int* cursor = (int*)(ws + STC_OFF_CUR);
    int* offs = (int*)(ws + STC_OFF_OFFS);
    int* ccol = (int*)(ws + STC_OFF_CCOL);
    float* cw = (float*)(ws + STC_OFF_CW);
    bf16* T0 = (bf16*)(ws + STC_OFF_T0);
    bf16* G1 = (bf16*)(ws + STC_OFF_G1);
    short* pk2 = (short*)(ws + STC_OFF_PK2);
    short* pk1 = (short*)(ws + STC_OFF_PK1);
    short* pkc = (short*)(ws + STC_OFF_PKC);

    stc_init<<<73, 256, 0, stream>>>((int*)(ws + STC_OFF_DEG),
                                     w1a, w1b, w1c, w2a, w2b, w2c, chW,
                                     pk1, pk2, pkc);
    stc_deg<<<(E + 255) / 256, 256, 0, stream>>>(ei, ew, deg, cnt, E);
    stc_scan<<<1, 256, 0, stream>>>(cnt, offs, STC_N);
    stc_scatter<<<(E + 255) / 256, 256, 0, stream>>>(ei, ew, deg, offs, cursor, ccol, cw, E);
    stc_tconv1m<<<STC_GBLK, 256, 0, stream>>>(X, pk1, b1a, b1b, b1c, T0);
    stc_gatherv<<<STC_N, 512, 0, stream>>>(T0, G1, offs, ccol, cw);
    stc_gcombconv2bn<<<STC_N, 512, 0, stream>>>(
        T0, G1, offs, ccol, cw, pkc, chB, pk2, b2a, b2b, b2c, gam, bet, out);
}

// Round 10
// 242.000 us; speedup vs baseline: 1.0653x; 1.0653x over previous
//
#include <hip/hip_runtime.h>
#include <hip/hip_bf16.h>

#define STC_N     5000
#define STC_TIN   16
#define STC_T1    14
#define STC_T2    12
#define STC_CIN   16
#define STC_CH    32
#define STC_CO    64
#define STC_BT1   56
#define STC_BT2   48
#define STC_RT1   17500      /* 280000/16 row-tiles */
#define STC_GBLK  1280
#define STC_GWAVE (STC_GBLK*4)
#define STC_ROWB1 1792       /* BT1*CH elements per node (transposed layout) */

#define STC_OFF_DEG   0
#define STC_OFF_CNT   20000
#define STC_OFF_CUR   40000
#define STC_OFF_DIS   60000
#define STC_OFF_OFFS  80000
#define STC_OFF_WN    100032
#define STC_OFF_CCOL  420032
#define STC_OFF_CW    740032
#define STC_OFF_T0    1060096
#define STC_OFF_G1    (STC_OFF_T0 + 17920000)
#define STC_OFF_G2    (STC_OFF_G1 + 17920000)
#define STC_OFF_PK2   (STC_OFF_G2 + 17920000)   /* 36 frags * 512 B */
#define STC_OFF_PK1   (STC_OFF_PK2 + 36864)     /* 12 frags */
#define STC_OFF_PKC   (STC_OFF_PK1 + 12288)     /* 6 frags */
#define STC_WS_REQ    (STC_OFF_PKC + 6144)

typedef __hip_bfloat16 bf16;
typedef short stc_s8 __attribute__((ext_vector_type(8)));
typedef float stc_f4 __attribute__((ext_vector_type(4)));

__device__ float stc_lo16(unsigned u) { return __uint_as_float(u << 16); }
__device__ float stc_hi16(unsigned u) { return __uint_as_float(u & 0xffff0000u); }
__device__ float stc_s2f(short s) {
    return __uint_as_float(((unsigned)(unsigned short)s) << 16);
}

__device__ short stc_f2bs(float f) {          /* f32 -> bf16 bits, RNE */
    unsigned u = __float_as_uint(f);
    u = (u + 0x7FFFu + ((u >> 16) & 1u)) >> 16;
    return (short)u;
}

__global__ void STConv_9972914061616_kernel() {}

__global__ void stc_fill(float* out, int n, float val) {
    int i = blockIdx.x * 256 + threadIdx.x;
    if (i < n) out[i] = val;
}

/* merged zero (blocks 0..58) + weight pack (blocks 59..72); independent work */
__global__ void stc_init(int* zp,
                         const float* w1a, const float* w1b, const float* w1c,
                         const float* w2a, const float* w2b, const float* w2c,
                         const float* chW,
                         short* pk1, short* pk2, short* pkc) {
    if (blockIdx.x < 59) {
        int i = blockIdx.x * 256 + threadIdx.x;
        if (i < 15000) zp[i] = 0;
        return;
    }
    int gid = (blockIdx.x - 59) * 256 + threadIdx.x;
    if (gid >= 54 * 64) return;
    int fi = gid >> 6;
    int lane = gid & 63;
    int j = lane & 15;
    int quad = lane >> 4;
    short f[8];
    if (fi < 36) {
        int s = fi % 3;
        int cc4 = fi / 3;
        int conv = cc4 >> 2;
        int c4 = cc4 & 3;
        const float* Wp = (conv == 0) ? w2a : ((conv == 1) ? w2b : w2c);
        int och = c4 * 16 + j;
        for (int i = 0; i < 8; ++i) {
            int cc = quad * 8 + i;
            f[i] = stc_f2bs(Wp[och * 96 + cc * 3 + s]);
        }
        for (int i = 0; i < 8; ++i) pk2[(fi * 64 + lane) * 8 + i] = f[i];
    } else if (fi < 48) {
        int t = fi - 36;
        int s = t & 1;
        int cj = t >> 1;
        int conv = cj >> 1;
        int jt = cj & 1;
        const float* Wp = (conv == 0) ? w1a : ((conv == 1) ? w1b : w1c);
        int och = jt * 16 + j;
        for (int i = 0; i < 8; ++i) {
            int k = s * 32 + quad * 8 + i;
            int kt = k >> 4;
            int c = k & 15;
            f[i] = (kt < 3) ? stc_f2bs(Wp[och * 48 + c * 3 + kt]) : (short)0;
        }
        for (int i = 0; i < 8; ++i) pk1[(t * 64 + lane) * 8 + i] = f[i];
    } else {
        int t = fi - 48;
        int s = t >> 1;
        int jt = t & 1;
        int d = jt * 16 + j;
        for (int i = 0; i < 8; ++i) {
            int c = quad * 8 + i;
            float w0 = chW[c * 32 + d];
            float w1 = chW[1024 + c * 32 + d];
            float w2 = chW[2048 + c * 32 + d];
            float v = (s == 0) ? (w0 - w2) : ((s == 1) ? -w1 : 2.0f * w2);
            f[i] = stc_f2bs(v);
        }
        for (int i = 0; i < 8; ++i) pkc[(t * 64 + lane) * 8 + i] = f[i];
    }
}

/* degree + count in one pass */
__global__ void stc_deg(const int* ei, const float* ew, float* deg, int* cnt, int E) {
    int e = blockIdx.x * 256 + threadIdx.x;
    if (e < E) {
        int r = ei[e];
        atomicAdd(&deg[r], ew[e]);
        atomicAdd(&cnt[r], 1);
    }
}

/* one-pass scan: 20 elems/thread in registers, ONE 8-round block scan */
__global__ void stc_scan(const int* cnt, int* offs, int n) {
    __shared__ int s[256];
    int tid = threadIdx.x;
    int base = tid * 20;
    int loc[20];
    int sum = 0;
#pragma unroll
    for (int k = 0; k < 20; ++k) {
        int i = base + k;
        int v = (i < n) ? cnt[i] : 0;
        loc[k] = sum;
        sum += v;
    }
    s[tid] = sum;
    __syncthreads();
    for (int off = 1; off < 256; off <<= 1) {
        int t = (tid >= off) ? s[tid - off] : 0;
        __syncthreads();
        s[tid] += t;
        __syncthreads();
    }
    int pre = (tid > 0) ? s[tid - 1] : 0;
#pragma unroll
    for (int k = 0; k < 20; ++k) {
        int i = base + k;
        if (i < n) offs[i] = pre + loc[k];
    }
    if (tid == 255) offs[n] = s[255];
}

/* scatter with inline sym-norm weight (deg is 20 KB, L2-hot) */
__global__ void stc_scatter(const int* ei, const float* ew, const float* deg,
                            const int* offs, int* cursor, int* ccol, float* cw,
                            int E) {
    int e = blockIdx.x * 256 + threadIdx.x;
    if (e < E) {
        int r = ei[e];
        int c = ei[E + e];
        float dr = deg[r];
        float dc = deg[c];
        float ir = (dr > 0.0f) ? rsqrtf(dr) : 0.0f;
        float ic = (dc > 0.0f) ? rsqrtf(dc) : 0.0f;
        int pos = atomicAdd(&cursor[r], 1);
        int slot = offs[r] + pos;
        ccol[slot] = c;
        cw[slot] = ir * ew[e] * ic;
    }
}

/* tconv1 as MFMA GEMM: C[280000 x 96] = A[280000 x 48] * B[48 x 96]. */
__global__ __launch_bounds__(256, 2) void stc_tconv1m(
    const float* X, const short* pk1,
    const float* B1, const float* B2, const float* B3,
    bf16* T0) {
    int lane = threadIdx.x & 63;
    int j = lane & 15;
    int quad = lane >> 4;
    int wave = blockIdx.x * 4 + (threadIdx.x >> 6);

    stc_s8 bfrag[3][2][2];
    for (int conv = 0; conv < 3; ++conv)
        for (int jt = 0; jt < 2; ++jt)
            for (int s = 0; s < 2; ++s) {
                int t = (conv * 2 + jt) * 2 + s;
                bfrag[conv][jt][s] = *(const stc_s8*)(pk1 + (t * 64 + lane) * 8);
            }
    float pb[2], qb[2], rb[2];
    for (int jt = 0; jt < 2; ++jt) {
        int och = jt * 16 + j;
        pb[jt] = B1[och];
        qb[jt] = B2[och];
        rb[jt] = B3[och];
    }

    for (int rt = wave; rt < STC_RT1; rt += STC_GWAVE) {
        int rm = rt * 16 + j;
        int n = rm % STC_N;
        int bt = rm / STC_N;
        int t = bt % STC_T1;
        int b = bt / STC_T1;

        int kt0 = quad >> 1;
        int c0 = (quad & 1) * 8;
        const float* xp0 = X + ((size_t)((b * STC_TIN + t + kt0) * STC_N + n)) * STC_CIN + c0;
        stc_s8 af0;
        for (int i = 0; i < 8; ++i) af0[i] = stc_f2bs(xp0[i]);

        stc_s8 af1;
        if (quad < 2) {
            const float* xp1 = X + ((size_t)((b * STC_TIN + t + 2) * STC_N + n)) * STC_CIN + c0;
            for (int i = 0; i < 8; ++i) af1[i] = stc_f2bs(xp1[i]);
        } else {
            for (int i = 0; i < 8; ++i) af1[i] = 0;
        }

        stc_f4 acc[6];
        for (int a = 0; a < 6; ++a) acc[a] = (stc_f4){0.0f, 0.0f, 0.0f, 0.0f};
        for (int conv = 0; conv < 3; ++conv) {
            for (int jt = 0; jt < 2; ++jt) {
                int a = conv * 2 + jt;
                acc[a] = __builtin_amdgcn_mfma_f32_16x16x32_bf16(
                    af0, bfrag[conv][jt][0], acc[a], 0, 0, 0);
                acc[a] = __builtin_amdgcn_mfma_f32_16x16x32_bf16(
                    af1, bfrag[conv][jt][1], acc[a], 0, 0, 0);
            }
        }

        for (int jt = 0; jt < 2; ++jt) {
            for (int reg = 0; reg < 4; ++reg) {
                float P = acc[jt][reg] + pb[jt];
                float Q = acc[2 + jt][reg] + qb[jt];
                float R = acc[4 + jt][reg] + rb[jt];
                float Qc = fminf(fmaxf(Q, -30.0f), 30.0f);
                float sg = 1.0f / (1.0f + __expf(-Qc));
                float h = P * sg + R;
                if (h < 0.0f) h = 0.0f;
                int row = rt * 16 + quad * 4 + reg;
                int nw = row % STC_N;
                int btw = row / STC_N;
                T0[(size_t)nw * STC_ROWB1 + btw * STC_CH + jt * 16 + j] =
                    __float2bfloat16(h);
            }
        }
    }
}

/* gather on transposed layout (R8-proven form: 256 thr, uint4, unroll 4 —
   widest loads minimize VMEM request count; R9 showed uint2/512thr is
   request-bound 30% slower despite higher occupancy). */
__global__ void stc_gatherv(const bf16* z, bf16* g, const int* offs,
                            const int* ccol, const float* cw) {
    int n = blockIdx.x;
    __shared__ int col_s[128];
    __shared__ float w_s[128];
    int beg = offs[n];
    int end = offs[n + 1];
    int cg = threadIdx.x & 3;
    int sl = threadIdx.x >> 2;
    int act = (sl < STC_BT1);
    float a0 = 0.f, a1 = 0.f, a2 = 0.f, a3 = 0.f;
    float a4 = 0.f, a5 = 0.f, a6 = 0.f, a7 = 0.f;
    const bf16* zb = z + sl * STC_CH + cg * 8;
    for (int chunk = beg; chunk < end; chunk += 128) {
        int m = end - chunk;
        if (m > 128) m = 128;
        if (threadIdx.x < m) {
            col_s[threadIdx.x] = ccol[chunk + threadIdx.x];
            w_s[threadIdx.x] = cw[chunk + threadIdx.x];
        }
        __syncthreads();
        if (act) {
            int i = 0;
            for (; i + 4 <= m; i += 4) {
                float w0 = w_s[i], w1 = w_s[i + 1], w2 = w_s[i + 2], w3 = w_s[i + 3];
                uint4 u0 = *(const uint4*)(zb + (size_t)col_s[i] * STC_ROWB1);
                uint4 u1 = *(const uint4*)(zb + (size_t)col_s[i + 1] * STC_ROWB1);
                uint4 u2 = *(const uint4*)(zb + (size_t)col_s[i + 2] * STC_ROWB1);
                uint4 u3 = *(const uint4*)(zb + (size_t)col_s[i + 3] * STC_ROWB1);
                a0 += w0 * stc_lo16(u0.x); a1 += w0 * stc_hi16(u0.x);
                a2 += w0 * stc_lo16(u0.y); a3 += w0 * stc_hi16(u0.y);
                a4 += w0 * stc_lo16(u0.z); a5 += w0 * stc_hi16(u0.z);
                a6 += w0 * stc_lo16(u0.w); a7 += w0 * stc_hi16(u0.w);
                a0 += w1 * stc_lo16(u1.x); a1 += w1 * stc_hi16(u1.x);
                a2 += w1 * stc_lo16(u1.y); a3 += w1 * stc_hi16(u1.y);
                a4 += w1 * stc_lo16(u1.z); a5 += w1 * stc_hi16(u1.z);
                a6 += w1 * stc_lo16(u1.w); a7 += w1 * stc_hi16(u1.w);
                a0 += w2 * stc_lo16(u2.x); a1 += w2 * stc_hi16(u2.x);
                a2 += w2 * stc_lo16(u2.y); a3 += w2 * stc_hi16(u2.y);
                a4 += w2 * stc_lo16(u2.z); a5 += w2 * stc_hi16(u2.z);
                a6 += w2 * stc_lo16(u2.w); a7 += w2 * stc_hi16(u2.w);
                a0 += w3 * stc_lo16(u3.x); a1 += w3 * stc_hi16(u3.x);
                a2 += w3 * stc_lo16(u3.y); a3 += w3 * stc_hi16(u3.y);
                a4 += w3 * stc_lo16(u3.z); a5 += w3 * stc_hi16(u3.z);
                a6 += w3 * stc_lo16(u3.w); a7 += w3 * stc_hi16(u3.w);
            }
            for (; i < m; ++i) {
                float w = w_s[i];
                uint4 u = *(const uint4*)(zb + (size_t)col_s[i] * STC_ROWB1);
                a0 += w * stc_lo16(u.x); a1 += w * stc_hi16(u.x);
                a2 += w * stc_lo16(u.y); a3 += w * stc_hi16(u.y);
                a4 += w * stc_lo16(u.z); a5 += w * stc_hi16(u.z);
                a6 += w * stc_lo16(u.w); a7 += w * stc_hi16(u.w);
            }
        }
        __syncthreads();
    }
    if (act) {
        unsigned p0 = ((unsigned)(unsigned short)stc_f2bs(a0)) |
                      (((unsigned)(unsigned short)stc_f2bs(a1)) << 16);
        unsigned p1 = ((unsigned)(unsigned short)stc_f2bs(a2)) |
                      (((unsigned)(unsigned short)stc_f2bs(a3)) << 16);
        unsigned p2 = ((unsigned)(unsigned short)stc_f2bs(a4)) |
                      (((unsigned)(unsigned short)stc_f2bs(a5)) << 16);
        unsigned p3 = ((unsigned)(unsigned short)stc_f2bs(a6)) |
                      (((unsigned)(unsigned short)stc_f2bs(a7)) << 16);
        uint4 o;
        o.x = p0; o.y = p1; o.z = p2; o.w = p3;
        *(uint4*)(g + (size_t)n * STC_ROWB1 + sl * STC_CH + cg * 8) = o;
    }
}

/* Fused second gather + cheb-combine + tconv2 + per-node BN (R8-proven
   structure) + s_setprio(1) around the MFMA clusters: co-resident blocks
   are at different phases, so MFMA waves get priority over gather-issuing
   waves on the same CU (T5: applies to phase-split schedules). */
__global__ __launch_bounds__(256, 2) void stc_gcombconv2bn(
    const bf16* T0, const bf16* G1,
    const int* offs, const int* ccol, const float* cw,
    const short* pkc, const float* chB,
    const short* pk2, const float* B1, const float* B2, const float* B3,
    const float* gamma, const float* beta, float* T2) {
    __shared__ short comb[64 * 40];   /* 5120 B */
    __shared__ short g2[64 * 40];     /* 5120 B */
    __shared__ short hb[48 * 72];     /* 6912 B */
    __shared__ int col_s[128];
    __shared__ float w_s[128];
    __shared__ float red[8];
    int lane = threadIdx.x & 63;
    int j = lane & 15;
    int quad = lane >> 4;
    int w = threadIdx.x >> 6;
    int n = blockIdx.x;               /* grid = 5000 blocks, 1 node each */

    /* ---- phase G: gather G2 rows for node n from G1 ---- */
    {
        int beg = offs[n];
        int end = offs[n + 1];
        int cg = threadIdx.x & 3;
        int sl = threadIdx.x >> 2;
        int act = (sl < STC_BT1);
        float a0 = 0.f, a1 = 0.f, a2 = 0.f, a3 = 0.f;
        float a4 = 0.f, a5 = 0.f, a6 = 0.f, a7 = 0.f;
        const bf16* zb = G1 + sl * STC_CH + cg * 8;
        for (int chunk = beg; chunk < end; chunk += 128) {
            int m = end - chunk;
            if (m > 128) m = 128;
            if (threadIdx.x < m) {
                col_s[threadIdx.x] = ccol[chunk + threadIdx.x];
                w_s[threadIdx.x] = cw[chunk + threadIdx.x];
            }
            __syncthreads();
            if (act) {
                int i = 0;
                for (; i + 4 <= m; i += 4) {
                    float w0 = w_s[i], w1 = w_s[i + 1], w2 = w_s[i + 2], w3 = w_s[i + 3];
                    uint4 u0 = *(const uint4*)(zb + (size_t)col_s[i] * STC_ROWB1);
                    uint4 u1 = *(const uint4*)(zb + (size_t)col_s[i + 1] * STC_ROWB1);
                    uint4 u2 = *(const uint4*)(zb + (size_t)col_s[i + 2] * STC_ROWB1);
                    uint4 u3 = *(const uint4*)(zb + (size_t)col_s[i + 3] * STC_ROWB1);
                    a0 += w0 * stc_lo16(u0.x); a1 += w0 * stc_hi16(u0.x);
                    a2 += w0 * stc_lo16(u0.y); a3 += w0 * stc_hi16(u0.y);
                    a4 += w0 * stc_lo16(u0.z); a5 += w0 * stc_hi16(u0.z);
                    a6 += w0 * stc_lo16(u0.w); a7 += w0 * stc_hi16(u0.w);
                    a0 += w1 * stc_lo16(u1.x); a1 += w1 * stc_hi16(u1.x);
                    a2 += w1 * stc_lo16(u1.y); a3 += w1 * stc_hi16(u1.y);
                    a4 += w1 * stc_lo16(u1.z); a5 += w1 * stc_hi16(u1.z);
                    a6 += w1 * stc_lo16(u1.w); a7 += w1 * stc_hi16(u1.w);
                    a0 += w2 * stc_lo16(u2.x); a1 += w2 * stc_hi16(u2.x);
                    a2 += w2 * stc_lo16(u2.y); a3 += w2 * stc_hi16(u2.y);
                    a4 += w2 * stc_lo16(u2.z); a5 += w2 * stc_hi16(u2.z);
                    a6 += w2 * stc_lo16(u2.w); a7 += w2 * stc_hi16(u2.w);
                    a0 += w3 * stc_lo16(u3.x); a1 += w3 * stc_hi16(u3.x);
                    a2 += w3 * stc_lo16(u3.y); a3 += w3 * stc_hi16(u3.y);
                    a4 += w3 * stc_lo16(u3.z); a5 += w3 * stc_hi16(u3.z);
                    a6 += w3 * stc_lo16(u3.w); a7 += w3 * stc_hi16(u3.w);
                }
                for (; i < m; ++i) {
                    float wv = w_s[i];
                    uint4 u = *(const uint4*)(zb + (size_t)col_s[i] * STC_ROWB1);
                    a0 += wv * stc_lo16(u.x); a1 += wv * stc_hi16(u.x);
                    a2 += wv * stc_lo16(u.y); a3 += wv * stc_hi16(u.y);
                    a4 += wv * stc_lo16(u.z); a5 += wv * stc_hi16(u.z);
                    a6 += wv * stc_lo16(u.w); a7 += wv * stc_hi16(u.w);
                }
            }
            __syncthreads();
        }
        /* inactive lanes (sl>=56) accumulated nothing -> write zeros */
        unsigned p0 = ((unsigned)(unsigned short)stc_f2bs(a0)) |
                      (((unsigned)(unsigned short)stc_f2bs(a1)) << 16);
        unsigned p1 = ((unsigned)(unsigned short)stc_f2bs(a2)) |
                      (((unsigned)(unsigned short)stc_f2bs(a3)) << 16);
        unsigned p2 = ((unsigned)(unsigned short)stc_f2bs(a4)) |
                      (((unsigned)(unsigned short)stc_f2bs(a5)) << 16);
        unsigned p3 = ((unsigned)(unsigned short)stc_f2bs(a6)) |
                      (((unsigned)(unsigned short)stc_f2bs(a7)) << 16);
        uint4* gp = (uint4*)(g2 + sl * 40 + cg * 8);
        uint4 o;
        o.x = p0; o.y = p1; o.z = p2; o.w = p3;
        *gp = o;
    }
    __syncthreads();

    /* ---- phase A: wave w combines tile t3 = w ---- */
    {
        stc_s8 cfrag[3][2];
        for (int s = 0; s < 3; ++s)
            for (int jt = 0; jt < 2; ++jt)
                cfrag[s][jt] = *(const stc_s8*)(pkc + ((s * 2 + jt) * 64 + lane) * 8);
        float bl0 = chB[j];
        float bl1 = chB[16 + j];
        size_t rm = (size_t)n * STC_BT1 + w * 16 + j;
        size_t abase = rm * STC_CH + quad * 8;
        stc_s8 a0 = *(const stc_s8*)(T0 + abase);
        stc_s8 a1 = *(const stc_s8*)(G1 + abase);
        stc_s8 a2 = *(const stc_s8*)(g2 + (w * 16 + j) * 40 + quad * 8);
        stc_f4 acc[2];
        acc[0] = (stc_f4){0.0f, 0.0f, 0.0f, 0.0f};
        acc[1] = (stc_f4){0.0f, 0.0f, 0.0f, 0.0f};
        __builtin_amdgcn_s_setprio(1);
        for (int jt = 0; jt < 2; ++jt) {
            acc[jt] = __builtin_amdgcn_mfma_f32_16x16x32_bf16(a0, cfrag[0][jt], acc[jt], 0, 0, 0);
            acc[jt] = __builtin_amdgcn_mfma_f32_16x16x32_bf16(a1, cfrag[1][jt], acc[jt], 0, 0, 0);
            acc[jt] = __builtin_amdgcn_mfma_f32_16x16x32_bf16(a2, cfrag[2][jt], acc[jt], 0, 0, 0);
        }
        __builtin_amdgcn_s_setprio(0);
        for (int jt = 0; jt < 2; ++jt) {
            float bl = (jt == 0) ? bl0 : bl1;
            for (int reg = 0; reg < 4; ++reg) {
                float h = acc[jt][reg] + bl;
                if (h < 0.0f) h = 0.0f;
                int row = w * 16 + quad * 4 + reg;
                comb[row * 40 + jt * 16 + j] = stc_f2bs(h);
            }
        }
    }
    __syncthreads();

    /* ---- phase B: wave w owns c4 = w for all 3 bt2-tiles ---- */
    stc_s8 bfrag[3][3];   /* [conv][s] */
    for (int conv = 0; conv < 3; ++conv)
        for (int s = 0; s < 3; ++s) {
            int fi = (conv * 4 + w) * 3 + s;
            bfrag[conv][s] = *(const stc_s8*)(pk2 + (fi * 64 + lane) * 8);
        }
    int och = w * 16 + j;
    float pb = B1[och];
    float qb = B2[och];
    float rb = B3[och];

    float lsum = 0.0f;
    for (int t3 = 0; t3 < 3; ++t3) {
        int btb = t3 * 16;
        int bt2 = btb + j;
        int b = bt2 / STC_T2;
        int t = bt2 % STC_T2;
        const short* ap = comb + (b * STC_T1 + t) * 40 + quad * 8;
        stc_s8 af0 = *(const stc_s8*)(ap);
        stc_s8 af1 = *(const stc_s8*)(ap + 40);
        stc_s8 af2 = *(const stc_s8*)(ap + 80);

        stc_f4 acc[3];   /* P, Q, R for this c4 slice */
        for (int a = 0; a < 3; ++a) acc[a] = (stc_f4){0.0f, 0.0f, 0.0f, 0.0f};
        __builtin_amdgcn_s_setprio(1);
        for (int conv = 0; conv < 3; ++conv) {
            acc[conv] = __builtin_amdgcn_mfma_f32_16x16x32_bf16(
                af0, bfrag[conv][0], acc[conv], 0, 0, 0);
            acc[conv] = __builtin_amdgcn_mfma_f32_16x16x32_bf16(
                af1, bfrag[conv][1], acc[conv], 0, 0, 0);
            acc[conv] = __builtin_amdgcn_mfma_f32_16x16x32_bf16(
                af2, bfrag[conv][2], acc[conv], 0, 0, 0);
        }
        __builtin_amdgcn_s_setprio(0);

        for (int reg = 0; reg < 4; ++reg) {
            float P = acc[0][reg] + pb;
            float Q = acc[1][reg] + qb;
            float R = acc[2][reg] + rb;
            float Qc = fminf(fmaxf(Q, -30.0f), 30.0f);
            float sg = 1.0f / (1.0f + __expf(-Qc));
            float h = P * sg + R;
            if (h < 0.0f) h = 0.0f;
            short hs = stc_f2bs(h);
            int row = btb + quad * 4 + reg;
            hb[row * 72 + w * 16 + j] = hs;
            lsum += stc_s2f(hs);
        }
    }
    /* wave partial -> LDS; barrier also publishes hb for phase C */
    for (int off = 32; off; off >>= 1) lsum += __shfl_xor(lsum, off);
    if (lane == 0) red[w] = lsum;
    __syncthreads();

    float mean = (red[0] + red[1] + red[2] + red[3]) * (1.0f / (STC_BT2 * STC_CO));

    /* variance: 256 threads x 12 elems */
    int colc = threadIdx.x & 63;
    int rw0 = threadIdx.x >> 6;
    float sq = 0.0f;
    for (int it = 0; it < 12; ++it) {
        int row = it * 4 + rw0;
        float d = stc_s2f(hb[row * 72 + colc]) - mean;
        sq += d * d;
    }
    for (int off = 32; off; off >>= 1) sq += __shfl_xor(sq, off);
    if (lane == 0) red[4 + w] = sq;
    __syncthreads();
    float var = (red[4] + red[5] + red[6] + red[7]) * (1.0f / (STC_BT2 * STC_CO));
    float istd = rsqrtf(var + 1e-5f);
    float scale = istd * gamma[n];
    float shift = beta[n] - mean * scale;
    for (int it = 0; it < 12; ++it) {
        int row = it * 4 + rw0;
        T2[((size_t)row * STC_N + n) * STC_CO + colc] =
            stc_s2f(hb[row * 72 + colc]) * scale + shift;
    }
}

extern "C" void kernel_launch(void* const* d_in, const int* in_sizes, int n_in,
                              void* d_out, int out_size, void* d_ws, size_t ws_size,
                              hipStream_t stream) {
    float* out = (float*)d_out;
    int outb = (out_size + 255) / 256;

    if (n_in < 19) {
        stc_fill<<<outb, 256, 0, stream>>>(out, out_size, 60.0f);
        return;
    }
    if (ws_size < (size_t)STC_WS_REQ) {
        stc_fill<<<outb, 256, 0, stream>>>(out, out_size, 50.0f);
        return;
    }

    const float* X = (const float*)d_in[0];
    const int* ei = (const int*)d_in[1];
    const float* ew = (const float*)d_in[2];
    const float* w1a = (const float*)d_in[3];
    const float* b1a = (const float*)d_in[4];
    const float* w1b = (const float*)d_in[5];
    const float* b1b = (const float*)d_in[6];
    const float* w1c = (const float*)d_in[7];
    const float* b1c = (const float*)d_in[8];
    const float* chW = (const float*)d_in[9];
    const float* chB = (const float*)d_in[10];
    const float* w2a = (const float*)d_in[11];
    const float* b2a = (const float*)d_in[12];
    const float* w2b = (const float*)d_in[13];
    const float* b2b = (const float*)d_in[14];
    const float* w2c = (const float*)d_in[15];
    const float* b2c = (const float*)d_in[16];
    const float* gam = (const float*)d_in[17];
    const float* bet = (const float*)d_in[18];
    int E = in_sizes[1] / 2;

    char* ws = (char*)d_ws;
    float* deg = (float*)(ws + STC_OFF_DEG);
    int* cnt = (int*)(ws + STC_OFF_CNT);
    int* cursor = (int*)(ws + STC_OFF_CUR);
    int* offs = (int*)(ws + STC_OFF_OFFS);
    int* ccol = (int*)(ws + STC_OFF_CCOL);
    float* cw = (float*)(ws + STC_OFF_CW);
    bf16* T0 = (bf16*)(ws + STC_OFF_T0);
    bf16* G1 = (bf16*)(ws + STC_OFF_G1);
    short* pk2 = (short*)(ws + STC_OFF_PK2);
    short* pk1 = (short*)(ws + STC_OFF_PK1);
    short* pkc = (short*)(ws + STC_OFF_PKC);

    stc_init<<<73, 256, 0, stream>>>((int*)(ws + STC_OFF_DEG),
                                     w1a, w1b, w1c, w2a, w2b, w2c, chW,
                                     pk1, pk2, pkc);
    stc_deg<<<(E + 255) / 256, 256, 0, stream>>>(ei, ew, deg, cnt, E);
    stc_scan<<<1, 256, 0, stream>>>(cnt, offs, STC_N);
    stc_scatter<<<(E + 255) / 256, 256, 0, stream>>>(ei, ew, deg, offs, cursor, ccol, cw, E);
    stc_tconv1m<<<STC_GBLK, 256, 0, stream>>>(X, pk1, b1a, b1b, b1c, T0);
    stc_gatherv<<<STC_N, 256, 0, stream>>>(T0, G1, offs, ccol, cw);
    stc_gcombconv2bn<<<STC_N, 256, 0, stream>>>(
        T0, G1, offs, ccol, cw, pkc, chB, pk2, b2a, b2b, b2c, gam, bet, out);
}